// Round 14
// baseline (429.868 us; speedup 1.0000x reference)
//
#include <hip/hip_runtime.h>

#define BB 32
#define LL 4096
#define DD 1024
#define GRID 1024  // 4 blocks/CU x 256 CUs; launch_bounds(256,4) => co-resident
#define K2T 48     // phase2: 64 ktiles x 16 jchunks = 1024 blocks
#define K3T 16     // phase3: 64 ktiles x 16 jchunks = 1024 blocks

typedef float vf4 __attribute__((ext_vector_type(4)));

static __device__ __forceinline__ int imax(int a, int b) { return a > b ? a : b; }
static __device__ __forceinline__ int imin(int a, int b) { return a < b ? a : b; }

static __device__ __forceinline__ vf4 ntld(const float* p) {
    return __builtin_nontemporal_load((const vf4*)p);
}

// ws float layout: sums[98304] | hmid[32768] | bar[256]
#define BAR_OFF 131072
// bar dwords: [0]=cnt1 [16]=flag1 [32]=cnt2 [48]=flag2

// K0: zero sums+hmid+bar (32832 f4) and out (8192 f4). 161 blocks x 256.
__global__ __launch_bounds__(256) void k0_zero(float* __restrict__ ws,
                                               float* __restrict__ out) {
    const int i = blockIdx.x * 256 + threadIdx.x;
    const float4 z = make_float4(0.f, 0.f, 0.f, 0.f);
    if (i < 32832) ((float4*)ws)[i] = z;
    else if (i < 32832 + 8192) ((float4*)out)[i - 32832] = z;
}

// Grid-wide barrier (R10-proven): device-scope atomics, single-use per call.
static __device__ __forceinline__ void gbar(unsigned* cnt, unsigned* flag, int nb) {
    __syncthreads();
    if (threadIdx.x == 0) {
        __threadfence();
        const unsigned old = __hip_atomic_fetch_add(cnt, 1u, __ATOMIC_ACQ_REL,
                                                    __HIP_MEMORY_SCOPE_AGENT);
        if ((int)old == nb - 1) {
            __hip_atomic_store(flag, 1u, __ATOMIC_RELEASE, __HIP_MEMORY_SCOPE_AGENT);
        } else {
            while (__hip_atomic_load(flag, __ATOMIC_ACQUIRE,
                                     __HIP_MEMORY_SCOPE_AGENT) == 0u)
                __builtin_amdgcn_s_sleep(1);
        }
        __threadfence();
    }
    __syncthreads();
}

// Add rows [beg,end) into acc: 8/4/1-deep (R7-proven), nt loads (R13-neutral).
static __device__ __forceinline__ void accum_rows_add(const float* __restrict__ hb,
                                                      int beg, int end, vf4& acc) {
    vf4 a0 = (vf4)(0.f);
    vf4 a1 = a0, a2 = a0, a3 = a0, a4 = a0, a5 = a0, a6 = a0, a7 = a0;
    int l = beg;
    for (; l + 8 <= end; l += 8) {
        a0 += ntld(hb + (size_t)(l + 0) * DD);
        a1 += ntld(hb + (size_t)(l + 1) * DD);
        a2 += ntld(hb + (size_t)(l + 2) * DD);
        a3 += ntld(hb + (size_t)(l + 3) * DD);
        a4 += ntld(hb + (size_t)(l + 4) * DD);
        a5 += ntld(hb + (size_t)(l + 5) * DD);
        a6 += ntld(hb + (size_t)(l + 6) * DD);
        a7 += ntld(hb + (size_t)(l + 7) * DD);
    }
    for (; l + 4 <= end; l += 4) {
        a0 += ntld(hb + (size_t)(l + 0) * DD);
        a1 += ntld(hb + (size_t)(l + 1) * DD);
        a2 += ntld(hb + (size_t)(l + 2) * DD);
        a3 += ntld(hb + (size_t)(l + 3) * DD);
    }
    for (; l < end; ++l) a0 += ntld(hb + (size_t)l * DD);
    acc += ((a0 + a1) + (a2 + a3)) + ((a4 + a5) + (a6 + a7));
}

static __device__ __forceinline__ float agload(const float* p) {
    return __hip_atomic_load(p, __ATOMIC_RELAXED, __HIP_MEMORY_SCOPE_AGENT);
}

__global__ __launch_bounds__(256, 4) void fused(const float* __restrict__ h,
                                                const int* __restrict__ sp1,
                                                const int* __restrict__ sp2,
                                                const float* __restrict__ W1,
                                                const float* __restrict__ b1,
                                                const float* __restrict__ W2,
                                                const float* __restrict__ b2,
                                                float* __restrict__ sums,
                                                float* __restrict__ hmid,
                                                float* __restrict__ out,
                                                unsigned* __restrict__ bar) {
    const int tid = threadIdx.x;
    const int bk = blockIdx.x;

    __shared__ float lds[BB * K2T];  // 6 KB, reused by phase 3
    __shared__ float icl[3 * BB];

    // ============ phase 1: span sums (R7/R13-proven body, G1=GRID) =========
    {
        int NC = 0;
#pragma unroll
        for (int b = 0; b < BB; ++b)
            NC += sp2[2 * b + 1] - sp1[2 * b] + 1;

        const int q = NC / GRID, r = NC % GRID;
        int c0 = bk * q + imin(bk, r);
        const int c1 = c0 + q + (bk < r ? 1 : 0);
        if (c0 < c1) {
            int b = 0, base = 0, s1, e1, s2, e2, len;
            for (;; ++b) {
                s1 = sp1[2 * b]; e1 = sp1[2 * b + 1];
                s2 = sp2[2 * b]; e2 = sp2[2 * b + 1];
                len = e2 - s1 + 1;
                if (c0 < base + len) break;
                base += len;
            }
            for (;;) {
                const int cend = imin(c1, base + len);
                const int rb = s1 + (c0 - base);
                const int re = s1 + (cend - base);
                const float* hb = h + (size_t)b * LL * DD + (size_t)tid * 4;
                float* dstb = sums + (size_t)b * 3 * DD + (size_t)tid * 4;
                const int lo[3] = {rb, imax(rb, e1 + 1), imax(rb, s2)};
                const int hi[3] = {imin(re, e1 + 1), imin(re, s2), re};
#pragma unroll
                for (int s = 0; s < 3; ++s) {
                    if (lo[s] < hi[s]) {
                        vf4 acc = (vf4)(0.f);
                        accum_rows_add(hb, lo[s], hi[s], acc);
                        float* d = dstb + s * DD;
                        atomicAdd(d + 0, acc.x); atomicAdd(d + 1, acc.y);
                        atomicAdd(d + 2, acc.z); atomicAdd(d + 3, acc.w);
                    }
                }
                c0 = cend;
                if (c0 >= c1) break;
                base += len; ++b;
                s1 = sp1[2 * b]; e1 = sp1[2 * b + 1];
                s2 = sp2[2 * b]; e2 = sp2[2 * b + 1];
                len = e2 - s1 + 1;
            }
        }
    }
    gbar(&bar[0], &bar[16], GRID);

    // ============ phase 2: hmid += (sums*ic) @ W1  (R11 spill-proof shape) ==
    {
        const int jb = bk & 15, kt = bk >> 4;   // 16 jb x 64 kt
        const int k0 = kt * K2T;
        if (tid < 3 * BB) {
            const int s = tid >> 5, b = tid & 31;
            const int s1 = sp1[2 * b], e1 = sp1[2 * b + 1];
            const int s2 = sp2[2 * b], e2 = sp2[2 * b + 1];
            const int cnt = (s == 0) ? (e1 + 1 - s1) : (s == 1) ? (s2 - e1 - 1)
                                                                : (e2 + 1 - s2);
            icl[tid] = 1.0f / (float)imax(cnt, 1);
        }
        __syncthreads();
        for (int i = tid; i < BB * K2T; i += 256) {
            const int b = i / K2T, kk = i - b * K2T;
            const int k = k0 + kk;
            lds[i] = agload(&sums[(size_t)b * (3 * DD) + k]) * icl[(k >> 10) * BB + b];
        }
        __syncthreads();

        const int tx = tid & 63, ty = tid >> 6;
        const int j = jb * 64 + tx;
        const float* c = lds + (ty * 8) * K2T;
        const float* w = W1 + (size_t)k0 * DD + j;

        float acc[8];
#pragma unroll
        for (int u = 0; u < 8; ++u) acc[u] = 0.f;

        for (int kk = 0; kk < K2T; kk += 4) {
            const float w0 = w[(size_t)(kk + 0) * DD];
            const float w1 = w[(size_t)(kk + 1) * DD];
            const float w2 = w[(size_t)(kk + 2) * DD];
            const float w3 = w[(size_t)(kk + 3) * DD];
#pragma unroll
            for (int u = 0; u < 8; ++u) {
                acc[u] = fmaf(c[u * K2T + kk + 0], w0, acc[u]);
                acc[u] = fmaf(c[u * K2T + kk + 1], w1, acc[u]);
                acc[u] = fmaf(c[u * K2T + kk + 2], w2, acc[u]);
                acc[u] = fmaf(c[u * K2T + kk + 3], w3, acc[u]);
            }
        }
#pragma unroll
        for (int u = 0; u < 8; ++u)
            atomicAdd(&hmid[(size_t)(ty * 8 + u) * DD + j], acc[u]);
    }
    gbar(&bar[32], &bar[48], GRID);

    // ============ phase 3: out = relu(hmid+b1) @ W2 + b2 ====================
    {
        const int jb = bk & 15, kt = bk >> 4;   // 16 jb x 64 kt
        const int k0 = kt * K3T;
        for (int i = tid; i < BB * K3T; i += 256) {
            const int b = i >> 4, kk = i & 15;
            lds[i] = fmaxf(agload(&hmid[(size_t)b * DD + (k0 + kk)]) + b1[k0 + kk], 0.f);
        }
        __syncthreads();

        const int tx = tid & 63, ty = tid >> 6;
        const int j = jb * 64 + tx;
        const float* a = lds + (ty * 8) * K3T;
        const float* w = W2 + (size_t)k0 * DD + j;

        float acc[8];
        const float bias = (kt == 0) ? b2[j] : 0.f;
#pragma unroll
        for (int u = 0; u < 8; ++u) acc[u] = bias;

        for (int kk = 0; kk < K3T; kk += 4) {
            const float w0 = w[(size_t)(kk + 0) * DD];
            const float w1 = w[(size_t)(kk + 1) * DD];
            const float w2 = w[(size_t)(kk + 2) * DD];
            const float w3 = w[(size_t)(kk + 3) * DD];
#pragma unroll
            for (int u = 0; u < 8; ++u) {
                acc[u] = fmaf(a[u * K3T + kk + 0], w0, acc[u]);
                acc[u] = fmaf(a[u * K3T + kk + 1], w1, acc[u]);
                acc[u] = fmaf(a[u * K3T + kk + 2], w2, acc[u]);
                acc[u] = fmaf(a[u * K3T + kk + 3], w3, acc[u]);
            }
        }
#pragma unroll
        for (int u = 0; u < 8; ++u)
            atomicAdd(&out[(size_t)(ty * 8 + u) * DD + j], acc[u]);
    }
}

extern "C" void kernel_launch(void* const* d_in, const int* in_sizes, int n_in,
                              void* d_out, int out_size, void* d_ws, size_t ws_size,
                              hipStream_t stream) {
    const float* h = (const float*)d_in[0];
    const int* sp1 = (const int*)d_in[1];
    const int* sp2 = (const int*)d_in[2];
    const float* W1 = (const float*)d_in[3];
    const float* b1 = (const float*)d_in[4];
    const float* W2 = (const float*)d_in[5];
    const float* b2 = (const float*)d_in[6];
    float* out = (float*)d_out;

    float* ws = (float*)d_ws;
    float* sums = ws;                       // 98304 floats
    float* hmid = ws + BB * 3 * DD;         // 32768 floats
    unsigned* bar = (unsigned*)(ws + BAR_OFF);

    k0_zero<<<161, 256, 0, stream>>>(ws, out);
    fused<<<GRID, 256, 0, stream>>>(h, sp1, sp2, W1, b1, W2, b2,
                                    sums, hmid, out, bar);
}

// Round 15
// 392.577 us; speedup vs baseline: 1.0950x; 1.0950x over previous
//
#include <hip/hip_runtime.h>

#define BB 32
#define LL 4096
#define DD 1024
#define GRID 1024  // 4 blocks/CU x 256 CUs; waves_per_eu(4,4) pins co-residency
#define K2T 48     // phase2: 64 ktiles x 16 jchunks = 1024 blocks
#define K3T 16     // phase3: 64 ktiles x 16 jchunks = 1024 blocks

typedef float vf4 __attribute__((ext_vector_type(4)));

static __device__ __forceinline__ int imax(int a, int b) { return a > b ? a : b; }
static __device__ __forceinline__ int imin(int a, int b) { return a < b ? a : b; }

static __device__ __forceinline__ vf4 ntld(const float* p) {
    return __builtin_nontemporal_load((const vf4*)p);
}

// ws float layout: sums[98304] | hmid[32768] | bar[256]
#define BAR_OFF 131072
// bar dwords: [0]=cnt1 [16]=flag1 [32]=cnt2 [48]=flag2

// K0: zero sums+hmid+bar (32832 f4) and out (8192 f4). 161 blocks x 256.
__global__ __launch_bounds__(256) void k0_zero(float* __restrict__ ws,
                                               float* __restrict__ out) {
    const int i = blockIdx.x * 256 + threadIdx.x;
    const float4 z = make_float4(0.f, 0.f, 0.f, 0.f);
    if (i < 32832) ((float4*)ws)[i] = z;
    else if (i < 32832 + 8192) ((float4*)out)[i - 32832] = z;
}

// Grid-wide barrier (R10-proven correct), with stronger sleep backoff.
static __device__ __forceinline__ void gbar(unsigned* cnt, unsigned* flag, int nb) {
    __syncthreads();
    if (threadIdx.x == 0) {
        __threadfence();
        const unsigned old = __hip_atomic_fetch_add(cnt, 1u, __ATOMIC_ACQ_REL,
                                                    __HIP_MEMORY_SCOPE_AGENT);
        if ((int)old == nb - 1) {
            __hip_atomic_store(flag, 1u, __ATOMIC_RELEASE, __HIP_MEMORY_SCOPE_AGENT);
        } else {
            while (__hip_atomic_load(flag, __ATOMIC_ACQUIRE,
                                     __HIP_MEMORY_SCOPE_AGENT) == 0u)
                __builtin_amdgcn_s_sleep(8);
        }
        __threadfence();
    }
    __syncthreads();
}

// Add rows [beg,end) into acc: 4-deep (16-float live set -> spill-proof).
static __device__ __forceinline__ void accum_rows_add(const float* __restrict__ hb,
                                                      int beg, int end, vf4& acc) {
    vf4 a0 = (vf4)(0.f);
    vf4 a1 = a0, a2 = a0, a3 = a0;
    int l = beg;
    for (; l + 4 <= end; l += 4) {
        a0 += ntld(hb + (size_t)(l + 0) * DD);
        a1 += ntld(hb + (size_t)(l + 1) * DD);
        a2 += ntld(hb + (size_t)(l + 2) * DD);
        a3 += ntld(hb + (size_t)(l + 3) * DD);
    }
    for (; l < end; ++l) a0 += ntld(hb + (size_t)l * DD);
    acc += (a0 + a1) + (a2 + a3);
}

static __device__ __forceinline__ float agload(const float* p) {
    return __hip_atomic_load(p, __ATOMIC_RELAXED, __HIP_MEMORY_SCOPE_AGENT);
}

__global__ __launch_bounds__(256) __attribute__((amdgpu_waves_per_eu(4, 4)))
void fused(const float* __restrict__ h,
           const int* __restrict__ sp1,
           const int* __restrict__ sp2,
           const float* __restrict__ W1,
           const float* __restrict__ b1,
           const float* __restrict__ W2,
           const float* __restrict__ b2,
           float* __restrict__ sums,
           float* __restrict__ hmid,
           float* __restrict__ out,
           unsigned* __restrict__ bar) {
    const int tid = threadIdx.x;
    const int bk = blockIdx.x;

    __shared__ float lds[BB * K2T];  // 6 KB, reused by phase 3
    __shared__ float icl[3 * BB];

    // ============ phase 1: span sums (R7/R13-proven body) ==================
    {
        int NC = 0;
#pragma unroll
        for (int b = 0; b < BB; ++b)
            NC += sp2[2 * b + 1] - sp1[2 * b] + 1;

        const int q = NC / GRID, r = NC % GRID;
        int c0 = bk * q + imin(bk, r);
        const int c1 = c0 + q + (bk < r ? 1 : 0);
        if (c0 < c1) {
            int b = 0, base = 0, s1, e1, s2, e2, len;
            for (;; ++b) {
                s1 = sp1[2 * b]; e1 = sp1[2 * b + 1];
                s2 = sp2[2 * b]; e2 = sp2[2 * b + 1];
                len = e2 - s1 + 1;
                if (c0 < base + len) break;
                base += len;
            }
            for (;;) {
                const int cend = imin(c1, base + len);
                const int rb = s1 + (c0 - base);
                const int re = s1 + (cend - base);
                const float* hb = h + (size_t)b * LL * DD + (size_t)tid * 4;
                float* dstb = sums + (size_t)b * 3 * DD + (size_t)tid * 4;
                const int lo[3] = {rb, imax(rb, e1 + 1), imax(rb, s2)};
                const int hi[3] = {imin(re, e1 + 1), imin(re, s2), re};
#pragma unroll
                for (int s = 0; s < 3; ++s) {
                    if (lo[s] < hi[s]) {
                        vf4 acc = (vf4)(0.f);
                        accum_rows_add(hb, lo[s], hi[s], acc);
                        float* d = dstb + s * DD;
                        atomicAdd(d + 0, acc.x); atomicAdd(d + 1, acc.y);
                        atomicAdd(d + 2, acc.z); atomicAdd(d + 3, acc.w);
                    }
                }
                c0 = cend;
                if (c0 >= c1) break;
                base += len; ++b;
                s1 = sp1[2 * b]; e1 = sp1[2 * b + 1];
                s2 = sp2[2 * b]; e2 = sp2[2 * b + 1];
                len = e2 - s1 + 1;
            }
        }
    }
    gbar(&bar[0], &bar[16], GRID);

    // ============ phase 2: hmid += (sums*ic) @ W1  (R11 spill-proof shape) ==
    {
        const int jb = bk & 15, kt = bk >> 4;   // 16 jb x 64 kt
        const int k0 = kt * K2T;
        if (tid < 3 * BB) {
            const int s = tid >> 5, b = tid & 31;
            const int s1 = sp1[2 * b], e1 = sp1[2 * b + 1];
            const int s2 = sp2[2 * b], e2 = sp2[2 * b + 1];
            const int cnt = (s == 0) ? (e1 + 1 - s1) : (s == 1) ? (s2 - e1 - 1)
                                                                : (e2 + 1 - s2);
            icl[tid] = 1.0f / (float)imax(cnt, 1);
        }
        __syncthreads();
        for (int i = tid; i < BB * K2T; i += 256) {
            const int b = i / K2T, kk = i - b * K2T;
            const int k = k0 + kk;
            lds[i] = agload(&sums[(size_t)b * (3 * DD) + k]) * icl[(k >> 10) * BB + b];
        }
        __syncthreads();

        const int tx = tid & 63, ty = tid >> 6;
        const int j = jb * 64 + tx;
        const float* c = lds + (ty * 8) * K2T;
        const float* w = W1 + (size_t)k0 * DD + j;

        float acc[8];
#pragma unroll
        for (int u = 0; u < 8; ++u) acc[u] = 0.f;

        for (int kk = 0; kk < K2T; kk += 4) {
            const float w0 = w[(size_t)(kk + 0) * DD];
            const float w1 = w[(size_t)(kk + 1) * DD];
            const float w2 = w[(size_t)(kk + 2) * DD];
            const float w3 = w[(size_t)(kk + 3) * DD];
#pragma unroll
            for (int u = 0; u < 8; ++u) {
                acc[u] = fmaf(c[u * K2T + kk + 0], w0, acc[u]);
                acc[u] = fmaf(c[u * K2T + kk + 1], w1, acc[u]);
                acc[u] = fmaf(c[u * K2T + kk + 2], w2, acc[u]);
                acc[u] = fmaf(c[u * K2T + kk + 3], w3, acc[u]);
            }
        }
#pragma unroll
        for (int u = 0; u < 8; ++u)
            atomicAdd(&hmid[(size_t)(ty * 8 + u) * DD + j], acc[u]);
    }
    gbar(&bar[32], &bar[48], GRID);

    // ============ phase 3: out = relu(hmid+b1) @ W2 + b2 ====================
    {
        const int jb = bk & 15, kt = bk >> 4;   // 16 jb x 64 kt
        const int k0 = kt * K3T;
        for (int i = tid; i < BB * K3T; i += 256) {
            const int b = i >> 4, kk = i & 15;
            lds[i] = fmaxf(agload(&hmid[(size_t)b * DD + (k0 + kk)]) + b1[k0 + kk], 0.f);
        }
        __syncthreads();

        const int tx = tid & 63, ty = tid >> 6;
        const int j = jb * 64 + tx;
        const float* a = lds + (ty * 8) * K3T;
        const float* w = W2 + (size_t)k0 * DD + j;

        float acc[8];
        const float bias = (kt == 0) ? b2[j] : 0.f;
#pragma unroll
        for (int u = 0; u < 8; ++u) acc[u] = bias;

        for (int kk = 0; kk < K3T; kk += 4) {
            const float w0 = w[(size_t)(kk + 0) * DD];
            const float w1 = w[(size_t)(kk + 1) * DD];
            const float w2 = w[(size_t)(kk + 2) * DD];
            const float w3 = w[(size_t)(kk + 3) * DD];
#pragma unroll
            for (int u = 0; u < 8; ++u) {
                acc[u] = fmaf(a[u * K3T + kk + 0], w0, acc[u]);
                acc[u] = fmaf(a[u * K3T + kk + 1], w1, acc[u]);
                acc[u] = fmaf(a[u * K3T + kk + 2], w2, acc[u]);
                acc[u] = fmaf(a[u * K3T + kk + 3], w3, acc[u]);
            }
        }
#pragma unroll
        for (int u = 0; u < 8; ++u)
            atomicAdd(&out[(size_t)(ty * 8 + u) * DD + j], acc[u]);
    }
}

extern "C" void kernel_launch(void* const* d_in, const int* in_sizes, int n_in,
                              void* d_out, int out_size, void* d_ws, size_t ws_size,
                              hipStream_t stream) {
    const float* h = (const float*)d_in[0];
    const int* sp1 = (const int*)d_in[1];
    const int* sp2 = (const int*)d_in[2];
    const float* W1 = (const float*)d_in[3];
    const float* b1 = (const float*)d_in[4];
    const float* W2 = (const float*)d_in[5];
    const float* b2 = (const float*)d_in[6];
    float* out = (float*)d_out;

    float* ws = (float*)d_ws;
    float* sums = ws;                       // 98304 floats
    float* hmid = ws + BB * 3 * DD;         // 32768 floats
    unsigned* bar = (unsigned*)(ws + BAR_OFF);

    k0_zero<<<161, 256, 0, stream>>>(ws, out);
    fused<<<GRID, 256, 0, stream>>>(h, sp1, sp2, W1, b1, W2, b2,
                                    sums, hmid, out, bar);
}

// Round 16
// 101.684 us; speedup vs baseline: 4.2275x; 3.8608x over previous
//
#include <hip/hip_runtime.h>

#define BB 32
#define LL 4096
#define DD 1024
#define G1 1024    // k1 grid (R7-proven)
#define K2T 96     // gemm1 k-tile: 32 ktiles over 3072
#define K3T 64     // gemm2 k-tile: 16 ktiles over 1024

typedef float vf4 __attribute__((ext_vector_type(4)));  // native vector: nt-load legal

static __device__ __forceinline__ int imax(int a, int b) { return a > b ? a : b; }
static __device__ __forceinline__ int imin(int a, int b) { return a < b ? a : b; }

// Non-temporal float4 load (R13: neutral vs cached, kept from proven build).
static __device__ __forceinline__ vf4 ntld(const float* p) {
    return __builtin_nontemporal_load((const vf4*)p);
}

// K0: zero sums (24576 f4) + hmid (8192 f4) + out (8192 f4).
__global__ __launch_bounds__(256) void k0_zero(float* __restrict__ sums_hmid,
                                               float* __restrict__ out) {
    const int i = blockIdx.x * 256 + threadIdx.x;
    const float4 z = make_float4(0.f, 0.f, 0.f, 0.f);
    if (i < 32768) ((float4*)sums_hmid)[i] = z;
    else ((float4*)out)[i - 32768] = z;
}

// Add rows [beg,end) into acc: 8-deep then 4-deep then scalar tail (R7-proven).
static __device__ __forceinline__ void accum_rows_add(const float* __restrict__ hb,
                                                      int beg, int end, vf4& acc) {
    vf4 a0 = (vf4)(0.f);
    vf4 a1 = a0, a2 = a0, a3 = a0, a4 = a0, a5 = a0, a6 = a0, a7 = a0;
    int l = beg;
    for (; l + 8 <= end; l += 8) {
        a0 += ntld(hb + (size_t)(l + 0) * DD);
        a1 += ntld(hb + (size_t)(l + 1) * DD);
        a2 += ntld(hb + (size_t)(l + 2) * DD);
        a3 += ntld(hb + (size_t)(l + 3) * DD);
        a4 += ntld(hb + (size_t)(l + 4) * DD);
        a5 += ntld(hb + (size_t)(l + 5) * DD);
        a6 += ntld(hb + (size_t)(l + 6) * DD);
        a7 += ntld(hb + (size_t)(l + 7) * DD);
    }
    for (; l + 4 <= end; l += 4) {
        a0 += ntld(hb + (size_t)(l + 0) * DD);
        a1 += ntld(hb + (size_t)(l + 1) * DD);
        a2 += ntld(hb + (size_t)(l + 2) * DD);
        a3 += ntld(hb + (size_t)(l + 3) * DD);
    }
    for (; l < end; ++l) {
        a0 += ntld(hb + (size_t)l * DD);
    }
    acc += ((a0 + a1) + (a2 + a3)) + ((a4 + a5) + (a6 + a7));
}

// K1 (R7 structure): row-granular balanced decomposition, register accum,
// 4-atomic flush per (batch,seg) piece into sums[B][3][D].
__global__ __launch_bounds__(256) void k1_sums(const float* __restrict__ h,
                                               const int* __restrict__ sp1,
                                               const int* __restrict__ sp2,
                                               float* __restrict__ sums) {
    const int tid = threadIdx.x;

    int NC = 0;
#pragma unroll
    for (int b = 0; b < BB; ++b)
        NC += sp2[2 * b + 1] - sp1[2 * b] + 1;

    const int q = NC / G1, r = NC % G1;
    const int bk = blockIdx.x;
    int c0 = bk * q + imin(bk, r);
    const int c1 = c0 + q + (bk < r ? 1 : 0);
    if (c0 >= c1) return;

    int b = 0, base = 0, s1, e1, s2, e2, len;
    for (;; ++b) {
        s1 = sp1[2 * b]; e1 = sp1[2 * b + 1];
        s2 = sp2[2 * b]; e2 = sp2[2 * b + 1];
        len = e2 - s1 + 1;
        if (c0 < base + len) break;
        base += len;
    }

    for (;;) {
        const int cend = imin(c1, base + len);
        const int rb = s1 + (c0 - base);
        const int re = s1 + (cend - base);
        const float* hb = h + (size_t)b * LL * DD + (size_t)tid * 4;
        float* dstb = sums + (size_t)b * 3 * DD + (size_t)tid * 4;
        const int lo[3] = {rb, imax(rb, e1 + 1), imax(rb, s2)};
        const int hi[3] = {imin(re, e1 + 1), imin(re, s2), re};
#pragma unroll
        for (int s = 0; s < 3; ++s) {
            if (lo[s] < hi[s]) {
                vf4 acc = (vf4)(0.f);
                accum_rows_add(hb, lo[s], hi[s], acc);
                float* d = dstb + s * DD;
                atomicAdd(d + 0, acc.x); atomicAdd(d + 1, acc.y);
                atomicAdd(d + 2, acc.z); atomicAdd(d + 3, acc.w);
            }
        }
        c0 = cend;
        if (c0 >= c1) break;
        base += len; ++b;
        s1 = sp1[2 * b]; e1 = sp1[2 * b + 1];
        s2 = sp2[2 * b]; e2 = sp2[2 * b + 1];
        len = e2 - s1 + 1;
    }
}

// K2: spill-proof GEMM1 (R11-proven). Block = 64 j-cols x 32 batches in LDS.
__global__ __launch_bounds__(256) void k2_gemm1(const float* __restrict__ sums,
                                                const int* __restrict__ sp1,
                                                const int* __restrict__ sp2,
                                                const float* __restrict__ W1,
                                                float* __restrict__ hmid) {
    __shared__ float cl[BB * K2T];   // [b][kk], 12 KB
    __shared__ float icl[3 * BB];    // [seg][b]
    const int tid = threadIdx.x;
    const int k0 = blockIdx.y * K2T;

    if (tid < 3 * BB) {
        const int s = tid >> 5, b = tid & 31;
        const int s1 = sp1[2 * b], e1 = sp1[2 * b + 1];
        const int s2 = sp2[2 * b], e2 = sp2[2 * b + 1];
        const int cnt = (s == 0) ? (e1 + 1 - s1) : (s == 1) ? (s2 - e1 - 1) : (e2 + 1 - s2);
        icl[tid] = 1.0f / (float)imax(cnt, 1);
    }
    __syncthreads();
    for (int i = tid; i < BB * K2T; i += 256) {
        const int b = i / K2T, kk = i - b * K2T;
        const int k = k0 + kk;
        cl[i] = sums[(size_t)b * (3 * DD) + k] * icl[(k >> 10) * BB + b];
    }
    __syncthreads();

    const int tx = tid & 63, ty = tid >> 6;
    const int j = blockIdx.x * 64 + tx;
    const float* c = cl + (ty * 8) * K2T;
    const float* w = W1 + (size_t)k0 * DD + j;

    float acc[8];
#pragma unroll
    for (int u = 0; u < 8; ++u) acc[u] = 0.f;

    for (int kk = 0; kk < K2T; kk += 4) {
        const float w0 = w[(size_t)(kk + 0) * DD];
        const float w1 = w[(size_t)(kk + 1) * DD];
        const float w2 = w[(size_t)(kk + 2) * DD];
        const float w3 = w[(size_t)(kk + 3) * DD];
#pragma unroll
        for (int u = 0; u < 8; ++u) {
            acc[u] = fmaf(c[u * K2T + kk + 0], w0, acc[u]);
            acc[u] = fmaf(c[u * K2T + kk + 1], w1, acc[u]);
            acc[u] = fmaf(c[u * K2T + kk + 2], w2, acc[u]);
            acc[u] = fmaf(c[u * K2T + kk + 3], w3, acc[u]);
        }
    }
#pragma unroll
    for (int u = 0; u < 8; ++u)
        atomicAdd(&hmid[(size_t)(ty * 8 + u) * DD + j], acc[u]);
}

// K3: spill-proof GEMM2 (R11-proven).
__global__ __launch_bounds__(256) void k3_gemm2(const float* __restrict__ hmid,
                                                const float* __restrict__ b1,
                                                const float* __restrict__ W2,
                                                const float* __restrict__ b2,
                                                float* __restrict__ out) {
    __shared__ float al[BB * K3T];   // [b][kk], 8 KB
    const int tid = threadIdx.x;
    const int k0 = blockIdx.y * K3T;

    for (int i = tid; i < BB * K3T; i += 256) {
        const int b = i >> 6, kk = i & 63;
        al[i] = fmaxf(hmid[(size_t)b * DD + (k0 + kk)] + b1[k0 + kk], 0.f);
    }
    __syncthreads();

    const int tx = tid & 63, ty = tid >> 6;
    const int j = blockIdx.x * 64 + tx;
    const float* a = al + (ty * 8) * K3T;
    const float* w = W2 + (size_t)k0 * DD + j;

    float acc[8];
    const float bias = (blockIdx.y == 0) ? b2[j] : 0.f;
#pragma unroll
    for (int u = 0; u < 8; ++u) acc[u] = bias;

    for (int kk = 0; kk < K3T; kk += 4) {
        const float w0 = w[(size_t)(kk + 0) * DD];
        const float w1 = w[(size_t)(kk + 1) * DD];
        const float w2 = w[(size_t)(kk + 2) * DD];
        const float w3 = w[(size_t)(kk + 3) * DD];
#pragma unroll
        for (int u = 0; u < 8; ++u) {
            acc[u] = fmaf(a[u * K3T + kk + 0], w0, acc[u]);
            acc[u] = fmaf(a[u * K3T + kk + 1], w1, acc[u]);
            acc[u] = fmaf(a[u * K3T + kk + 2], w2, acc[u]);
            acc[u] = fmaf(a[u * K3T + kk + 3], w3, acc[u]);
        }
    }
#pragma unroll
    for (int u = 0; u < 8; ++u)
        atomicAdd(&out[(size_t)(ty * 8 + u) * DD + j], acc[u]);
}

extern "C" void kernel_launch(void* const* d_in, const int* in_sizes, int n_in,
                              void* d_out, int out_size, void* d_ws, size_t ws_size,
                              hipStream_t stream) {
    const float* h = (const float*)d_in[0];
    const int* sp1 = (const int*)d_in[1];
    const int* sp2 = (const int*)d_in[2];
    const float* W1 = (const float*)d_in[3];
    const float* b1 = (const float*)d_in[4];
    const float* W2 = (const float*)d_in[5];
    const float* b2 = (const float*)d_in[6];
    float* out = (float*)d_out;

    float* sums = (float*)d_ws;            // BB*3*DD floats
    float* hmid = sums + BB * 3 * DD;      // BB*DD floats (contiguous after sums)

    k0_zero<<<160, 256, 0, stream>>>((float*)d_ws, out);
    k1_sums<<<G1, 256, 0, stream>>>(h, sp1, sp2, sums);
    k2_gemm1<<<dim3(DD / 64, 3 * DD / K2T), 256, 0, stream>>>(sums, sp1, sp2, W1, hmid);
    k3_gemm2<<<dim3(DD / 64, DD / K3T), 256, 0, stream>>>(hmid, b1, W2, b2, out);
}